// Round 5
// baseline (360.686 us; speedup 1.0000x reference)
//
#include <hip/hip_runtime.h>

#define BATCH 16
#define CH    512
#define NSP   1024
#define HIDD  2048

typedef __bf16 bf16x8 __attribute__((ext_vector_type(8)));
typedef float floatx4 __attribute__((ext_vector_type(4)));

__device__ __forceinline__ float bf2f(unsigned short u) {
    union { unsigned int i; float f; } v; v.i = ((unsigned int)u) << 16; return v.f;
}
__device__ __forceinline__ unsigned short f2bf(float f) {
    union { float f; unsigned int i; } v; v.f = f;
    unsigned int i = v.i;
    return (unsigned short)((i + 0x7FFFu + ((i >> 16) & 1u)) >> 16);
}

// async global->LDS, 16B per lane; LDS dst is wave-uniform base + lane*16
__device__ __forceinline__ void gload16(const void* g, void* l) {
    __builtin_amdgcn_global_load_lds(
        (__attribute__((address_space(1))) unsigned int*)(g),
        (__attribute__((address_space(3))) unsigned int*)(l),
        16, 0, 0);
}
#define MEMFENCE asm volatile("" ::: "memory")

// ---------------------------------------------------------------------------
// C = A (MxK, row-major) * B^T  (Bm is NxK row-major). 128x128 tile, BK=32,
// 4 waves, 4x4 mfma 16x16x32 per wave.
// AITER-style K-loop: A staged to LDS (3-buffer, distance-2 prefetch,
// XOR bank swizzle), B loaded straight to VGPRs (distance-1, L2-resident).
// Exactly 6 vmem ops per iter (2 global_load_lds + 4 B-loads) =>
// raw "s_waitcnt vmcnt(6); s_barrier" retires tile it's A-stage while
// it+1/it+2 prefetches stay in flight across the barrier.
// MAP: 0 scores: XCD owns 2 batches; 1 PV: XCD owns 2 batches;
//      2 FFN1: plain n-fastest (r3 layout); 3 out: XCD owns 16 n-tiles.
// EPI: 0 scale->bf16 ; 1 plain->bf16 ; 2 +bias,relu->bf16 ;
//      4 transposed fp32: C[i][j] -> out[(j>>10)*CH*NSP + i*NSP + (j&1023)]
//         + bias[i] + resid[same]
// ---------------------------------------------------------------------------
template<int EPI, int MAP>
__global__ __launch_bounds__(256, 3)
void gemm_bt(const unsigned short* __restrict__ A,
             const unsigned short* __restrict__ Bm,
             void* __restrict__ Cout,
             int Nn, int K,
             long sAb, long sBb, long sCb,
             const float* __restrict__ bias, float scale,
             const float* __restrict__ resid)
{
    __shared__ unsigned short sA[3][128 * 32];   // 3 x 8 KB (A only)

    const int tid  = threadIdx.x;
    const int lane = tid & 63;
    const int w    = tid >> 6;        // wave 0..3
    const int quad = lane >> 4;
    const int l15  = lane & 15;
    const int mw   = (w >> 1) * 64;   // wave's m offset in tile
    const int nw   = (w & 1) * 64;    // wave's n offset in tile

    // block-id decode (XCD = F & 7 round-robin where used)
    const int F = blockIdx.x;
    int m0, n0, b;
    if constexpr (MAP == 0) {        // 1024 blocks: 2 batches/XCD, 8x8 tiles
        const int xcd = F & 7, s = F >> 3;
        b = xcd + ((s >> 6) << 3);
        const int j = s & 63; m0 = (j >> 3) << 7; n0 = (j & 7) << 7;
    } else if constexpr (MAP == 1) { // 512 blocks: 2 batches/XCD, 8x4 tiles
        const int xcd = F & 7, s = F >> 3;
        b = xcd + ((s >> 5) << 3);
        const int j = s & 31; m0 = (j >> 2) << 7; n0 = (j & 3) << 7;
    } else if constexpr (MAP == 2) { // plain n-fastest (16 n-tiles)
        b = 0; m0 = (F >> 4) << 7; n0 = (F & 15) << 7;
    } else {                         // 512 blocks: 16 n-tiles/XCD x 4 m
        const int xcd = F & 7, s = F >> 3;
        b = 0; m0 = (s & 3) << 7; n0 = ((xcd << 4) + (s >> 2)) << 7;
    }

    A  += (size_t)b * sAb;
    Bm += (size_t)b * sBb;

    // A staging: wave w stages tile rows [w*32, w*32+32) via 2 gload16
    // (16 rows each). Granule swizzle: LDS(row,s) = global(row, s^((row>>1)&3))
    const int srow = lane >> 2;                       // 0..15
    const int sg   = (lane & 3) ^ ((lane >> 3) & 3);  // swizzled global granule
    const unsigned short* pA = A + (size_t)(m0 + w * 32 + srow) * K + sg * 8;
    const size_t rowskip16 = (size_t)16 * K;
    const int woff = w * 1024;        // wave LDS base (32 rows * 32 shorts)
    const int rslot = ((l15 >> 1) & 3);   // reader swizzle slot

    // B fragment base: lane reads B[n0+nw+ni*16+l15][k + quad*8 ..+8)
    const unsigned short* pBf = Bm + (size_t)(n0 + nw + l15) * K + quad * 8;
    const size_t bstride = (size_t)16 * K;   // per-ni row step

    floatx4 acc[4][4];
#pragma unroll
    for (int i = 0; i < 4; i++)
#pragma unroll
        for (int j = 0; j < 4; j++) acc[i][j] = (floatx4){0.f, 0.f, 0.f, 0.f};

    const int nIter = K >> 5;   // even for all our shapes (16/32/64)
    const int kLast = K - 32;

    bf16x8 bP[4], bQ[4];   // ping-pong B fragment sets

    // ---- prologue: stage A(0)->buf0, A(1)->buf1, load B(0)->bP ----
    {
        unsigned short* d0 = &sA[0][0] + woff;
        unsigned short* d1 = &sA[1][0] + woff;
        gload16(pA,                 d0);
        gload16(pA + rowskip16,     d0 + 512);
        gload16(pA + 32,            d1);
        gload16(pA + 32 + rowskip16, d1 + 512);
        MEMFENCE;   // keep B loads after the A-stage ops (vmcnt ordering)
#pragma unroll
        for (int ni = 0; ni < 4; ni++)
            bP[ni] = *(const bf16x8*)(pBf + ni * bstride);
        MEMFENCE;
    }

    auto body = [&](int it, bf16x8* bcur, bf16x8* bnext) {
        // tile 'it' A-stage retired (6 newer vmem ops stay in flight)
        asm volatile("s_waitcnt vmcnt(6)\n\ts_barrier" ::: "memory");

        // stage A(it+2) into buffer (it+2)%3  (clamped dummy at tail)
        int r = it; while (r >= 3) r -= 3;          // it%3, cheap scalar
        int rs = r + 2; if (rs >= 3) rs -= 3;       // (it+2)%3
        const int kst = (it + 2) * 32 <= kLast ? (it + 2) * 32 : kLast;
        unsigned short* dS = &sA[0][0] + rs * 4096 + woff;
        gload16(pA + kst,             dS);
        gload16(pA + kst + rowskip16, dS + 512);
        MEMFENCE;
        // load B(it+1) fragments (clamped dummy at tail)
        const int kb = (it + 1) * 32 <= kLast ? (it + 1) * 32 : kLast;
#pragma unroll
        for (int ni = 0; ni < 4; ni++)
            bnext[ni] = *(const bf16x8*)(pBf + ni * bstride + kb);
        MEMFENCE;

        // A fragments from LDS buffer it%3
        const unsigned short* bufR = &sA[0][0] + r * 4096;
        bf16x8 af[4];
#pragma unroll
        for (int mi = 0; mi < 4; mi++)
            af[mi] = *(const bf16x8*)(bufR + (mw + mi * 16 + l15) * 32
                                      + (quad ^ rslot) * 8);
#pragma unroll
        for (int mi = 0; mi < 4; mi++)
#pragma unroll
            for (int ni = 0; ni < 4; ni++)
                acc[mi][ni] = __builtin_amdgcn_mfma_f32_16x16x32_bf16(
                    af[mi], bcur[ni], acc[mi][ni], 0, 0, 0);
    };

    for (int it = 0; it < nIter; it += 2) {   // unroll-2: B sets ping-pong
        body(it,     bP, bQ);
        body(it + 1, bQ, bP);
    }

    // epilogue: D row = quad*4 + reg, col = lane&15  (m89/m91-verified layout)
    if constexpr (EPI == 4) {
        float* Of = (float*)Cout;
#pragma unroll
        for (int ni = 0; ni < 4; ni++) {
            const int j  = n0 + nw + ni * 16 + l15;   // flattened (batch, n_sp)
            const int bb = j >> 10, ns = j & 1023;
            const size_t cbase = (size_t)bb * CH * NSP + ns;
#pragma unroll
            for (int mi = 0; mi < 4; mi++) {
                const int ibase = m0 + mw + mi * 16 + quad * 4;
#pragma unroll
                for (int r2 = 0; r2 < 4; r2++) {
                    const int c = ibase + r2;
                    const size_t a = cbase + (size_t)c * NSP;
                    Of[a] = acc[mi][ni][r2] + bias[c] + resid[a];
                }
            }
        }
    } else {
        unsigned short* Cb = (unsigned short*)Cout + (size_t)b * sCb;
#pragma unroll
        for (int ni = 0; ni < 4; ni++) {
            const int n = n0 + nw + ni * 16 + l15;
            float bv = 0.f;
            if constexpr (EPI == 2) bv = bias[n];
#pragma unroll
            for (int mi = 0; mi < 4; mi++) {
                const int mbase = m0 + mw + mi * 16 + quad * 4;
#pragma unroll
                for (int r2 = 0; r2 < 4; r2++) {
                    float v = acc[mi][ni][r2];
                    if constexpr (EPI == 0) v *= scale;
                    if constexpr (EPI == 2) v = fmaxf(v + bv, 0.f);
                    Cb[(size_t)(mbase + r2) * Nn + n] = f2bf(v);
                }
            }
        }
    }
}

// x [B][C][N] fp32 -> Xbf [B][C][N] bf16 and XT [B][N][C] bf16
__global__ __launch_bounds__(256)
void pack_x_kernel(const float* __restrict__ x,
                   unsigned short* __restrict__ Xbf,
                   unsigned short* __restrict__ XT)
{
    __shared__ float tile[32][33];
    const int tx = threadIdx.x, ty = threadIdx.y;
    const int n0 = blockIdx.x * 32, c0 = blockIdx.y * 32, b = blockIdx.z;
    const size_t base = (size_t)b * CH * NSP;
#pragma unroll
    for (int i = ty; i < 32; i += 8) {
        float v = x[base + (size_t)(c0 + i) * NSP + n0 + tx];
        tile[i][tx] = v;
        Xbf[base + (size_t)(c0 + i) * NSP + n0 + tx] = f2bf(v);
    }
    __syncthreads();
    const size_t tbase = (size_t)b * NSP * CH;
#pragma unroll
    for (int i = ty; i < 32; i += 8)
        XT[tbase + (size_t)(n0 + i) * CH + c0 + tx] = f2bf(tile[tx][i]);
}

__global__ __launch_bounds__(256)
void cast_bf16_kernel(const float* __restrict__ src,
                      unsigned short* __restrict__ dst, int n)
{
    int i = blockIdx.x * 256 + threadIdx.x;
    if (i < n) dst[i] = f2bf(src[i]);
}

// in-place row softmax on bf16 scores, rows of length NSP=1024
__global__ __launch_bounds__(256)
void softmax_kernel(unsigned short* __restrict__ S)
{
    const int row = blockIdx.x;
    unsigned short* p = S + (size_t)row * NSP;
    const int t = threadIdx.x;

    ushort4 u = ((const ushort4*)p)[t];
    float v0 = bf2f(u.x), v1 = bf2f(u.y), v2 = bf2f(u.z), v3 = bf2f(u.w);

    float m = fmaxf(fmaxf(v0, v1), fmaxf(v2, v3));
#pragma unroll
    for (int off = 32; off > 0; off >>= 1) m = fmaxf(m, __shfl_xor(m, off));
    __shared__ float redmax[4], redsum[4];
    const int wid = t >> 6;
    if ((t & 63) == 0) redmax[wid] = m;
    __syncthreads();
    m = fmaxf(fmaxf(redmax[0], redmax[1]), fmaxf(redmax[2], redmax[3]));

    v0 = __expf(v0 - m); v1 = __expf(v1 - m);
    v2 = __expf(v2 - m); v3 = __expf(v3 - m);
    float s = v0 + v1 + v2 + v3;
#pragma unroll
    for (int off = 32; off > 0; off >>= 1) s += __shfl_xor(s, off);
    if ((t & 63) == 0) redsum[wid] = s;
    __syncthreads();
    s = redsum[0] + redsum[1] + redsum[2] + redsum[3];

    const float inv = 1.0f / s;
    ushort4 o;
    o.x = f2bf(v0 * inv); o.y = f2bf(v1 * inv);
    o.z = f2bf(v2 * inv); o.w = f2bf(v3 * inv);
    ((ushort4*)p)[t] = o;
}

extern "C" void kernel_launch(void* const* d_in, const int* in_sizes, int n_in,
                              void* d_out, int out_size, void* d_ws, size_t ws_size,
                              hipStream_t stream)
{
    const float* x  = (const float*)d_in[0];
    const float* w1 = (const float*)d_in[1];
    const float* b1 = (const float*)d_in[2];
    const float* w2 = (const float*)d_in[3];
    const float* b2 = (const float*)d_in[4];
    float* out = (float*)d_out;

    char* ws = (char*)d_ws;
    unsigned short* Xbf = (unsigned short*)ws; ws += (size_t)BATCH * CH * NSP * 2;   // 16 MB
    unsigned short* XT  = (unsigned short*)ws; ws += (size_t)BATCH * NSP * CH * 2;   // 16 MB
    unsigned short* W1b = (unsigned short*)ws; ws += (size_t)HIDD * CH * 2;          //  2 MB
    unsigned short* W2b = (unsigned short*)ws; ws += (size_t)CH * HIDD * 2;          //  2 MB
    unsigned short* P   = (unsigned short*)ws; ws += (size_t)BATCH * NSP * NSP * 2;  // 32 MB
    unsigned short* O   = (unsigned short*)ws; ws += (size_t)BATCH * NSP * CH * 2;   // 16 MB
    unsigned short* Hb  = (unsigned short*)ws; ws += (size_t)BATCH * NSP * HIDD * 2; // 64 MB

    const dim3 blk(256);

    // pack inputs to bf16 (X and X^T), weights to bf16
    pack_x_kernel<<<dim3(NSP / 32, CH / 32, BATCH), dim3(32, 8), 0, stream>>>(x, Xbf, XT);
    cast_bf16_kernel<<<dim3((HIDD * CH) / 256), blk, 0, stream>>>(w1, W1b, HIDD * CH);
    cast_bf16_kernel<<<dim3((CH * HIDD) / 256), blk, 0, stream>>>(w2, W2b, CH * HIDD);

    // S = scale * XT * XT^T   (per batch)  -> bf16 scores in P
    gemm_bt<0, 0><<<dim3(1024), blk, 0, stream>>>(
        XT, XT, P, NSP, CH,
        (long)NSP * CH, (long)NSP * CH, (long)NSP * NSP, nullptr,
        0.04419417382415922f, nullptr);

    // row softmax in place
    softmax_kernel<<<dim3(BATCH * NSP), blk, 0, stream>>>(P);

    // O = P * X^T  (B^T operand = Xbf [C][N])
    gemm_bt<1, 1><<<dim3(512), blk, 0, stream>>>(
        P, Xbf, O, CH, NSP,
        (long)NSP * NSP, (long)CH * NSP, (long)NSP * CH, nullptr, 1.f, nullptr);

    // H = relu(O * W1^T + b1)   (batches flattened into M)
    gemm_bt<2, 2><<<dim3(2048), blk, 0, stream>>>(
        O, W1b, Hb, HIDD, CH, 0, 0, 0, b1, 1.f, nullptr);

    // out = (W2 * H^T)[c][b*n] + b2[c] + x   — transposed epilogue
    gemm_bt<4, 3><<<dim3(512), blk, 0, stream>>>(
        W2b, Hb, out, BATCH * NSP, HIDD, 0, 0, 0, b2, 1.f, x);
}

// Round 6
// 301.172 us; speedup vs baseline: 1.1976x; 1.1976x over previous
//
#include <hip/hip_runtime.h>

#define BATCH 16
#define CH    512
#define NSP   1024
#define HIDD  2048

typedef __bf16 bf16x8 __attribute__((ext_vector_type(8)));
typedef float floatx4 __attribute__((ext_vector_type(4)));

__device__ __forceinline__ float bf2f(unsigned short u) {
    union { unsigned int i; float f; } v; v.i = ((unsigned int)u) << 16; return v.f;
}
__device__ __forceinline__ unsigned short f2bf(float f) {
    union { float f; unsigned int i; } v; v.f = f;
    unsigned int i = v.i;
    return (unsigned short)((i + 0x7FFFu + ((i >> 16) & 1u)) >> 16);
}

// async global->LDS, 16B per lane; LDS dst is wave-uniform base + lane*16
__device__ __forceinline__ void gload16(const void* g, void* l) {
    __builtin_amdgcn_global_load_lds(
        (__attribute__((address_space(1))) unsigned int*)(g),
        (__attribute__((address_space(3))) unsigned int*)(l),
        16, 0, 0);
}

// ---------------------------------------------------------------------------
// Standard GEMM: C = A (MxK, rm) * B^T (Bm NxK rm). 128x128 tile, BK=32,
// 4 waves, 4x4 mfma 16x16x32. Single-barrier LDS double-buffer (r3-verified).
// XOR bank swizzle on 16B granules -> 0 LDS bank conflicts (r2-verified).
// MAP: 0 scores: XCD owns 2 batches; 1 PV: XCD owns 2 batches;
//      3 out: XCD owns 16 n-tiles x 4 m.
// EPI: 0 scale->bf16 ; 1 plain->bf16 ;
//      4 transposed fp32: C[i][j] -> out[(j>>10)*CH*NSP + i*NSP + (j&1023)]
//         + bias[i] + resid[same]
// ---------------------------------------------------------------------------
template<int EPI, int MAP>
__global__ __launch_bounds__(256, 4)
void gemm_bt(const unsigned short* __restrict__ A,
             const unsigned short* __restrict__ Bm,
             void* __restrict__ Cout,
             int Nn, int K,
             long sAb, long sBb, long sCb,
             const float* __restrict__ bias, float scale,
             const float* __restrict__ resid)
{
    __shared__ unsigned short sA[2][128 * 32];   // 2 x 8 KB
    __shared__ unsigned short sB[2][128 * 32];

    const int tid  = threadIdx.x;
    const int lane = tid & 63;
    const int w    = tid >> 6;        // wave 0..3
    const int quad = lane >> 4;
    const int l15  = lane & 15;
    const int mw   = (w >> 1) * 64;
    const int nw   = (w & 1) * 64;

    const int F = blockIdx.x;
    int m0, n0, b;
    if constexpr (MAP == 0) {        // 1024 blocks: 2 batches/XCD, 8x8 tiles
        const int xcd = F & 7, s = F >> 3;
        b = xcd + ((s >> 6) << 3);
        const int j = s & 63; m0 = (j >> 3) << 7; n0 = (j & 7) << 7;
    } else if constexpr (MAP == 1) { // 512 blocks: 2 batches/XCD, 8x4 tiles
        const int xcd = F & 7, s = F >> 3;
        b = xcd + ((s >> 5) << 3);
        const int j = s & 31; m0 = (j >> 2) << 7; n0 = (j & 3) << 7;
    } else {                         // 512 blocks: 16 n-tiles/XCD x 4 m
        const int xcd = F & 7, s = F >> 3;
        b = 0; m0 = (s & 3) << 7; n0 = ((xcd << 4) + (s >> 2)) << 7;
    }

    A  += (size_t)b * sAb;
    Bm += (size_t)b * sBb;

    const int srow = lane >> 2;                       // 0..15
    const int sg   = (lane & 3) ^ ((lane >> 3) & 3);  // swizzled global granule
    const unsigned short* pA = A  + (size_t)(m0 + w * 32 + srow) * K + sg * 8;
    const unsigned short* pB = Bm + (size_t)(n0 + w * 32 + srow) * K + sg * 8;
    const size_t rowskip16 = (size_t)16 * K;
    const int woff = w * 1024;
    const int rslot = ((l15 >> 1) & 3);

    floatx4 acc[4][4];
#pragma unroll
    for (int i = 0; i < 4; i++)
#pragma unroll
        for (int j = 0; j < 4; j++) acc[i][j] = (floatx4){0.f, 0.f, 0.f, 0.f};

    const int nIter = K >> 5;

    {
        unsigned short* dA = &sA[0][0] + woff;
        unsigned short* dB = &sB[0][0] + woff;
        gload16(pA,             dA);
        gload16(pA + rowskip16, dA + 512);
        gload16(pB,             dB);
        gload16(pB + rowskip16, dB + 512);
    }

    for (int it = 0; it < nIter; ++it) {
        __syncthreads();   // vmcnt(0) drain: tile 'it' resident in buf it&1

        if (it + 1 < nIter) {
            const int koff = (it + 1) << 5;
            unsigned short* dA = &sA[(it + 1) & 1][0] + woff;
            unsigned short* dB = &sB[(it + 1) & 1][0] + woff;
            gload16(pA + koff,             dA);
            gload16(pA + koff + rowskip16, dA + 512);
            gload16(pB + koff,             dB);
            gload16(pB + koff + rowskip16, dB + 512);
        }

        const unsigned short* bufA = &sA[it & 1][0];
        const unsigned short* bufB = &sB[it & 1][0];
        bf16x8 af[4], bfr[4];
#pragma unroll
        for (int mi = 0; mi < 4; mi++)
            af[mi] = *(const bf16x8*)(bufA + (mw + mi * 16 + l15) * 32
                                      + (quad ^ rslot) * 8);
#pragma unroll
        for (int ni = 0; ni < 4; ni++)
            bfr[ni] = *(const bf16x8*)(bufB + (nw + ni * 16 + l15) * 32
                                       + (quad ^ rslot) * 8);
#pragma unroll
        for (int mi = 0; mi < 4; mi++)
#pragma unroll
            for (int ni = 0; ni < 4; ni++)
                acc[mi][ni] = __builtin_amdgcn_mfma_f32_16x16x32_bf16(
                    af[mi], bfr[ni], acc[mi][ni], 0, 0, 0);
    }

    // epilogue: D row = quad*4 + reg, col = lane&15  (m89/m91-verified layout)
    if constexpr (EPI == 4) {
        float* Of = (float*)Cout;
#pragma unroll
        for (int ni = 0; ni < 4; ni++) {
            const int j  = n0 + nw + ni * 16 + l15;
            const int bb = j >> 10, ns = j & 1023;
            const size_t cbase = (size_t)bb * CH * NSP + ns;
#pragma unroll
            for (int mi = 0; mi < 4; mi++) {
                const int ibase = m0 + mw + mi * 16 + quad * 4;
#pragma unroll
                for (int r = 0; r < 4; r++) {
                    const int c = ibase + r;
                    const size_t a = cbase + (size_t)c * NSP;
                    Of[a] = acc[mi][ni][r] + bias[c] + resid[a];
                }
            }
        }
    } else {
        unsigned short* Cb = (unsigned short*)Cout + (size_t)b * sCb;
#pragma unroll
        for (int ni = 0; ni < 4; ni++) {
            const int n = n0 + nw + ni * 16 + l15;
#pragma unroll
            for (int mi = 0; mi < 4; mi++) {
                const int mbase = m0 + mw + mi * 16 + quad * 4;
#pragma unroll
                for (int r = 0; r < 4; r++) {
                    float v = acc[mi][ni][r];
                    if constexpr (EPI == 0) v *= scale;
                    Cb[(size_t)(mbase + r) * Nn + n] = f2bf(v);
                }
            }
        }
    }
}

// ---------------------------------------------------------------------------
// FFN1 big-tile GEMM: Hb = relu(O * W1^T + b1). 256x128 block tile, BK=32,
// 4 waves, wave tile 128x64 (acc 8x4) -> 32 MFMA (~155 cyc) per iter against
// the same 6 staging loads: 2x arithmetic intensity vs standard tile.
// ---------------------------------------------------------------------------
__global__ __launch_bounds__(256, 2)
void ffn1_big(const unsigned short* __restrict__ A,   // O  [16384][512]
              const unsigned short* __restrict__ Bm,  // W1 [2048][512]
              unsigned short* __restrict__ Cout,      // Hb [16384][2048]
              const float* __restrict__ bias)
{
    const int K = CH, Nn = HIDD;
    __shared__ unsigned short sA[2][256 * 32];   // 2 x 16 KB
    __shared__ unsigned short sB[2][128 * 32];   // 2 x  8 KB

    const int tid  = threadIdx.x;
    const int lane = tid & 63;
    const int w    = tid >> 6;
    const int quad = lane >> 4;
    const int l15  = lane & 15;
    const int mw   = (w >> 1) * 128;
    const int nw   = (w & 1) * 64;

    const int F = blockIdx.x;              // 1024 blocks, n-fastest
    const int m0 = (F >> 4) << 8;          // 64 m-tiles of 256
    const int n0 = (F & 15) << 7;          // 16 n-tiles of 128

    const int srow = lane >> 2;
    const int sg   = (lane & 3) ^ ((lane >> 3) & 3);
    const unsigned short* pA = A  + (size_t)(m0 + w * 64 + srow) * K + sg * 8;
    const unsigned short* pB = Bm + (size_t)(n0 + w * 32 + srow) * K + sg * 8;
    const size_t rowskip16 = (size_t)16 * K;
    const int woffA = w * 2048;            // 64 rows * 32 shorts
    const int woffB = w * 1024;            // 32 rows * 32 shorts
    const int rslot = ((l15 >> 1) & 3);

    floatx4 acc[8][4];
#pragma unroll
    for (int i = 0; i < 8; i++)
#pragma unroll
        for (int j = 0; j < 4; j++) acc[i][j] = (floatx4){0.f, 0.f, 0.f, 0.f};

    const int nIter = K >> 5;   // 16

    {
        unsigned short* dA = &sA[0][0] + woffA;
        unsigned short* dB = &sB[0][0] + woffB;
        gload16(pA,                 dA);
        gload16(pA +     rowskip16, dA + 512);
        gload16(pA + 2 * rowskip16, dA + 1024);
        gload16(pA + 3 * rowskip16, dA + 1536);
        gload16(pB,                 dB);
        gload16(pB +     rowskip16, dB + 512);
    }

    for (int it = 0; it < nIter; ++it) {
        __syncthreads();

        if (it + 1 < nIter) {
            const int koff = (it + 1) << 5;
            unsigned short* dA = &sA[(it + 1) & 1][0] + woffA;
            unsigned short* dB = &sB[(it + 1) & 1][0] + woffB;
            gload16(pA + koff,                 dA);
            gload16(pA + koff +     rowskip16, dA + 512);
            gload16(pA + koff + 2 * rowskip16, dA + 1024);
            gload16(pA + koff + 3 * rowskip16, dA + 1536);
            gload16(pB + koff,                 dB);
            gload16(pB + koff +     rowskip16, dB + 512);
        }

        const unsigned short* bufA = &sA[it & 1][0];
        const unsigned short* bufB = &sB[it & 1][0];
        bf16x8 af[8], bfr[4];
#pragma unroll
        for (int mi = 0; mi < 8; mi++)
            af[mi] = *(const bf16x8*)(bufA + (mw + mi * 16 + l15) * 32
                                      + (quad ^ rslot) * 8);
#pragma unroll
        for (int ni = 0; ni < 4; ni++)
            bfr[ni] = *(const bf16x8*)(bufB + (nw + ni * 16 + l15) * 32
                                       + (quad ^ rslot) * 8);
#pragma unroll
        for (int mi = 0; mi < 8; mi++)
#pragma unroll
            for (int ni = 0; ni < 4; ni++)
                acc[mi][ni] = __builtin_amdgcn_mfma_f32_16x16x32_bf16(
                    af[mi], bfr[ni], acc[mi][ni], 0, 0, 0);
    }

    // epilogue: +bias, relu -> bf16
#pragma unroll
    for (int ni = 0; ni < 4; ni++) {
        const int n = n0 + nw + ni * 16 + l15;
        const float bv = bias[n];
#pragma unroll
        for (int mi = 0; mi < 8; mi++) {
            const int mbase = m0 + mw + mi * 16 + quad * 4;
#pragma unroll
            for (int r = 0; r < 4; r++)
                Cout[(size_t)(mbase + r) * Nn + n] =
                    f2bf(fmaxf(acc[mi][ni][r] + bv, 0.f));
        }
    }
}

// x [B][C][N] fp32 -> Xbf [B][C][N] bf16 and XT [B][N][C] bf16
__global__ __launch_bounds__(256)
void pack_x_kernel(const float* __restrict__ x,
                   unsigned short* __restrict__ Xbf,
                   unsigned short* __restrict__ XT)
{
    __shared__ float tile[32][33];
    const int tx = threadIdx.x, ty = threadIdx.y;
    const int n0 = blockIdx.x * 32, c0 = blockIdx.y * 32, b = blockIdx.z;
    const size_t base = (size_t)b * CH * NSP;
#pragma unroll
    for (int i = ty; i < 32; i += 8) {
        float v = x[base + (size_t)(c0 + i) * NSP + n0 + tx];
        tile[i][tx] = v;
        Xbf[base + (size_t)(c0 + i) * NSP + n0 + tx] = f2bf(v);
    }
    __syncthreads();
    const size_t tbase = (size_t)b * NSP * CH;
#pragma unroll
    for (int i = ty; i < 32; i += 8)
        XT[tbase + (size_t)(n0 + i) * CH + c0 + tx] = f2bf(tile[tx][i]);
}

__global__ __launch_bounds__(256)
void cast_bf16_kernel(const float* __restrict__ src,
                      unsigned short* __restrict__ dst, int n)
{
    int i = blockIdx.x * 256 + threadIdx.x;
    if (i < n) dst[i] = f2bf(src[i]);
}

// in-place row softmax on bf16 scores, rows of length NSP=1024
__global__ __launch_bounds__(256)
void softmax_kernel(unsigned short* __restrict__ S)
{
    const int row = blockIdx.x;
    unsigned short* p = S + (size_t)row * NSP;
    const int t = threadIdx.x;

    ushort4 u = ((const ushort4*)p)[t];
    float v0 = bf2f(u.x), v1 = bf2f(u.y), v2 = bf2f(u.z), v3 = bf2f(u.w);

    float m = fmaxf(fmaxf(v0, v1), fmaxf(v2, v3));
#pragma unroll
    for (int off = 32; off > 0; off >>= 1) m = fmaxf(m, __shfl_xor(m, off));
    __shared__ float redmax[4], redsum[4];
    const int wid = t >> 6;
    if ((t & 63) == 0) redmax[wid] = m;
    __syncthreads();
    m = fmaxf(fmaxf(redmax[0], redmax[1]), fmaxf(redmax[2], redmax[3]));

    v0 = __expf(v0 - m); v1 = __expf(v1 - m);
    v2 = __expf(v2 - m); v3 = __expf(v3 - m);
    float s = v0 + v1 + v2 + v3;
#pragma unroll
    for (int off = 32; off > 0; off >>= 1) s += __shfl_xor(s, off);
    if ((t & 63) == 0) redsum[wid] = s;
    __syncthreads();
    s = redsum[0] + redsum[1] + redsum[2] + redsum[3];

    const float inv = 1.0f / s;
    ushort4 o;
    o.x = f2bf(v0 * inv); o.y = f2bf(v1 * inv);
    o.z = f2bf(v2 * inv); o.w = f2bf(v3 * inv);
    ((ushort4*)p)[t] = o;
}

extern "C" void kernel_launch(void* const* d_in, const int* in_sizes, int n_in,
                              void* d_out, int out_size, void* d_ws, size_t ws_size,
                              hipStream_t stream)
{
    const float* x  = (const float*)d_in[0];
    const float* w1 = (const float*)d_in[1];
    const float* b1 = (const float*)d_in[2];
    const float* w2 = (const float*)d_in[3];
    const float* b2 = (const float*)d_in[4];
    float* out = (float*)d_out;

    char* ws = (char*)d_ws;
    unsigned short* Xbf = (unsigned short*)ws; ws += (size_t)BATCH * CH * NSP * 2;   // 16 MB
    unsigned short* XT  = (unsigned short*)ws; ws += (size_t)BATCH * NSP * CH * 2;   // 16 MB
    unsigned short* W1b = (unsigned short*)ws; ws += (size_t)HIDD * CH * 2;          //  2 MB
    unsigned short* W2b = (unsigned short*)ws; ws += (size_t)CH * HIDD * 2;          //  2 MB
    unsigned short* P   = (unsigned short*)ws; ws += (size_t)BATCH * NSP * NSP * 2;  // 32 MB
    unsigned short* O   = (unsigned short*)ws; ws += (size_t)BATCH * NSP * CH * 2;   // 16 MB
    unsigned short* Hb  = (unsigned short*)ws; ws += (size_t)BATCH * NSP * HIDD * 2; // 64 MB

    const dim3 blk(256);

    // pack inputs to bf16 (X and X^T), weights to bf16
    pack_x_kernel<<<dim3(NSP / 32, CH / 32, BATCH), dim3(32, 8), 0, stream>>>(x, Xbf, XT);
    cast_bf16_kernel<<<dim3((HIDD * CH) / 256), blk, 0, stream>>>(w1, W1b, HIDD * CH);
    cast_bf16_kernel<<<dim3((CH * HIDD) / 256), blk, 0, stream>>>(w2, W2b, CH * HIDD);

    // S = scale * XT * XT^T   (per batch)  -> bf16 scores in P
    gemm_bt<0, 0><<<dim3(1024), blk, 0, stream>>>(
        XT, XT, P, NSP, CH,
        (long)NSP * CH, (long)NSP * CH, (long)NSP * NSP, nullptr,
        0.04419417382415922f, nullptr);

    // row softmax in place
    softmax_kernel<<<dim3(BATCH * NSP), blk, 0, stream>>>(P);

    // O = P * X^T  (B^T operand = Xbf [C][N])
    gemm_bt<1, 1><<<dim3(512), blk, 0, stream>>>(
        P, Xbf, O, CH, NSP,
        (long)NSP * NSP, (long)CH * NSP, (long)NSP * CH, nullptr, 1.f, nullptr);

    // H = relu(O * W1^T + b1)   — big-tile kernel, plain n-fastest map
    ffn1_big<<<dim3(1024), blk, 0, stream>>>(O, W1b, Hb, b1);

    // out = (W2 * H^T)[c][b*n] + b2[c] + x   — transposed epilogue
    gemm_bt<4, 3><<<dim3(512), blk, 0, stream>>>(
        W2b, Hb, out, BATCH * NSP, HIDD, 0, 0, 0, b2, 1.f, x);
}

// Round 7
// 278.584 us; speedup vs baseline: 1.2947x; 1.0811x over previous
//
#include <hip/hip_runtime.h>

#define BATCH 16
#define CH    512
#define NSP   1024
#define HIDD  2048

typedef __bf16 bf16x8 __attribute__((ext_vector_type(8)));
typedef float floatx4 __attribute__((ext_vector_type(4)));

__device__ __forceinline__ float bf2f(unsigned short u) {
    union { unsigned int i; float f; } v; v.i = ((unsigned int)u) << 16; return v.f;
}
__device__ __forceinline__ unsigned short f2bf(float f) {
    union { float f; unsigned int i; } v; v.f = f;
    unsigned int i = v.i;
    return (unsigned short)((i + 0x7FFFu + ((i >> 16) & 1u)) >> 16);
}

// async global->LDS, 16B per lane; LDS dst is wave-uniform base + lane*16
__device__ __forceinline__ void gload16(const void* g, void* l) {
    __builtin_amdgcn_global_load_lds(
        (__attribute__((address_space(1))) unsigned int*)(g),
        (__attribute__((address_space(3))) unsigned int*)(l),
        16, 0, 0);
}
#define MEMFENCE asm volatile("" ::: "memory")

// ---------------------------------------------------------------------------
// C = A (MxK, rm) * B^T (Bm NxK rm). 128x128 tile, BK=32, 4 waves,
// 4x4 mfma 16x16x32 per wave. XOR bank swizzle -> 0 conflicts (r2-verified).
//
// K-loop (AITER-style, r6 analysis): 3 LDS buffers, distance-2 prefetch,
// exactly 4 gload16 per wave per iter (2 A + 2 B). Loop barrier is raw
//   s_waitcnt vmcnt(4); s_barrier
// i.e. wait only for this wave's tile-'it' staging (4 older ops) while the
// 4+4 ops for tiles it+1/it+2 stay IN FLIGHT across the barrier. Each wave
// stages its own share and waits for its own share, so post-barrier the
// whole tile is resident. __syncthreads (which drains vmcnt(0)) is never
// used inside the loop -- that drain was the ~90% stall (r6 post-mortem).
// Tail iters issue clamped dummy prefetches to keep vmcnt arithmetic uniform.
//
// MAP: 0 scores: XCD owns 2 batches; 1 PV: XCD owns 2 batches;
//      2 plain n-fastest (16 n-tiles); 3 out: XCD owns 16 n-tiles x 4 m.
// EPI: 0 scale->bf16 ; 1 plain->bf16 ; 2 +bias,relu->bf16 ;
//      4 transposed fp32: C[i][j] -> out[(j>>10)*CH*NSP + i*NSP + (j&1023)]
//         + bias[i] + resid[same]
// ---------------------------------------------------------------------------
template<int EPI, int MAP>
__global__ __launch_bounds__(256, 3)
void gemm_bt(const unsigned short* __restrict__ A,
             const unsigned short* __restrict__ Bm,
             void* __restrict__ Cout,
             int Nn, int K,
             long sAb, long sBb, long sCb,
             const float* __restrict__ bias, float scale,
             const float* __restrict__ resid)
{
    __shared__ unsigned short sA[3][128 * 32];   // 3 x 8 KB
    __shared__ unsigned short sB[3][128 * 32];   // 3 x 8 KB

    const int tid  = threadIdx.x;
    const int lane = tid & 63;
    const int w    = tid >> 6;        // wave 0..3
    const int quad = lane >> 4;
    const int l15  = lane & 15;
    const int mw   = (w >> 1) * 64;
    const int nw   = (w & 1) * 64;

    const int F = blockIdx.x;
    int m0, n0, b;
    if constexpr (MAP == 0) {        // 1024 blocks: 2 batches/XCD, 8x8 tiles
        const int xcd = F & 7, s = F >> 3;
        b = xcd + ((s >> 6) << 3);
        const int j = s & 63; m0 = (j >> 3) << 7; n0 = (j & 7) << 7;
    } else if constexpr (MAP == 1) { // 512 blocks: 2 batches/XCD, 8x4 tiles
        const int xcd = F & 7, s = F >> 3;
        b = xcd + ((s >> 5) << 3);
        const int j = s & 31; m0 = (j >> 2) << 7; n0 = (j & 3) << 7;
    } else if constexpr (MAP == 2) { // plain n-fastest, 16 n-tiles
        b = 0; m0 = (F >> 4) << 7; n0 = (F & 15) << 7;
    } else {                         // 512 blocks: 16 n-tiles/XCD x 4 m
        const int xcd = F & 7, s = F >> 3;
        b = 0; m0 = (s & 3) << 7; n0 = ((xcd << 4) + (s >> 2)) << 7;
    }

    A  += (size_t)b * sAb;
    Bm += (size_t)b * sBb;

    // staging: wave w covers tile rows [w*32, w*32+32); each gload16 fills
    // 16 rows (lane>>2 = row, lane&3 = LDS granule slot). Granule swizzle:
    // LDS(row,s) = global(row, s^((row>>1)&3)).
    const int srow = lane >> 2;                       // 0..15
    const int sg   = (lane & 3) ^ ((lane >> 3) & 3);  // swizzled global granule
    const unsigned short* pA = A  + (size_t)(m0 + w * 32 + srow) * K + sg * 8;
    const unsigned short* pB = Bm + (size_t)(n0 + w * 32 + srow) * K + sg * 8;
    const size_t rowskip16 = (size_t)16 * K;
    const int woff = w * 1024;
    const int rslot = ((l15 >> 1) & 3);

    floatx4 acc[4][4];
#pragma unroll
    for (int i = 0; i < 4; i++)
#pragma unroll
        for (int j = 0; j < 4; j++) acc[i][j] = (floatx4){0.f, 0.f, 0.f, 0.f};

    const int nIter = K >> 5;
    const int kLast = K - 32;

    // prologue: stage tile 0 -> buf0, tile 1 -> buf1 (8 ops outstanding)
    {
        unsigned short* dA0 = &sA[0][0] + woff;
        unsigned short* dB0 = &sB[0][0] + woff;
        gload16(pA,                  dA0);
        gload16(pA + rowskip16,      dA0 + 512);
        gload16(pB,                  dB0);
        gload16(pB + rowskip16,      dB0 + 512);
        unsigned short* dA1 = &sA[1][0] + woff;
        unsigned short* dB1 = &sB[1][0] + woff;
        gload16(pA + 32,             dA1);
        gload16(pA + 32 + rowskip16, dA1 + 512);
        gload16(pB + 32,             dB1);
        gload16(pB + 32 + rowskip16, dB1 + 512);
        MEMFENCE;
    }

    int bcur = 0, bpf = 2;   // buffer of tile 'it' / buffer for tile it+2
    for (int it = 0; it < nIter; ++it) {
        // tile 'it' staging retired; it+1/it+2 stay in flight
        asm volatile("s_waitcnt vmcnt(4)\n\ts_barrier" ::: "memory");

        // prefetch tile it+2 into buf bpf (clamped dummy at tail)
        const int kpf = (it + 2) * 32 <= kLast ? (it + 2) * 32 : kLast;
        unsigned short* dA = &sA[0][0] + bpf * 4096 + woff;
        unsigned short* dB = &sB[0][0] + bpf * 4096 + woff;
        gload16(pA + kpf,             dA);
        gload16(pA + kpf + rowskip16, dA + 512);
        gload16(pB + kpf,             dB);
        gload16(pB + kpf + rowskip16, dB + 512);
        MEMFENCE;

        const unsigned short* bufA = &sA[0][0] + bcur * 4096;
        const unsigned short* bufB = &sB[0][0] + bcur * 4096;
        bf16x8 af[4], bfr[4];
#pragma unroll
        for (int mi = 0; mi < 4; mi++)
            af[mi] = *(const bf16x8*)(bufA + (mw + mi * 16 + l15) * 32
                                      + (quad ^ rslot) * 8);
#pragma unroll
        for (int ni = 0; ni < 4; ni++)
            bfr[ni] = *(const bf16x8*)(bufB + (nw + ni * 16 + l15) * 32
                                       + (quad ^ rslot) * 8);
#pragma unroll
        for (int mi = 0; mi < 4; mi++)
#pragma unroll
            for (int ni = 0; ni < 4; ni++)
                acc[mi][ni] = __builtin_amdgcn_mfma_f32_16x16x32_bf16(
                    af[mi], bfr[ni], acc[mi][ni], 0, 0, 0);

        bcur = bcur == 2 ? 0 : bcur + 1;
        bpf  = bpf  == 2 ? 0 : bpf  + 1;
    }
    // drain dummy prefetches before endpgm (LDS is reallocated to next block)
    asm volatile("s_waitcnt vmcnt(0)" ::: "memory");

    // epilogue: D row = quad*4 + reg, col = lane&15  (m89/m91-verified layout)
    if constexpr (EPI == 4) {
        float* Of = (float*)Cout;
#pragma unroll
        for (int ni = 0; ni < 4; ni++) {
            const int j  = n0 + nw + ni * 16 + l15;
            const int bb = j >> 10, ns = j & 1023;
            const size_t cbase = (size_t)bb * CH * NSP + ns;
#pragma unroll
            for (int mi = 0; mi < 4; mi++) {
                const int ibase = m0 + mw + mi * 16 + quad * 4;
#pragma unroll
                for (int r = 0; r < 4; r++) {
                    const int c = ibase + r;
                    const size_t a = cbase + (size_t)c * NSP;
                    Of[a] = acc[mi][ni][r] + bias[c] + resid[a];
                }
            }
        }
    } else {
        unsigned short* Cb = (unsigned short*)Cout + (size_t)b * sCb;
#pragma unroll
        for (int ni = 0; ni < 4; ni++) {
            const int n = n0 + nw + ni * 16 + l15;
            float bv = 0.f;
            if constexpr (EPI == 2) bv = bias[n];
#pragma unroll
            for (int mi = 0; mi < 4; mi++) {
                const int mbase = m0 + mw + mi * 16 + quad * 4;
#pragma unroll
                for (int r = 0; r < 4; r++) {
                    float v = acc[mi][ni][r];
                    if constexpr (EPI == 0) v *= scale;
                    if constexpr (EPI == 2) v = fmaxf(v + bv, 0.f);
                    Cb[(size_t)(mbase + r) * Nn + n] = f2bf(v);
                }
            }
        }
    }
}

// x [B][C][N] fp32 -> Xbf [B][C][N] bf16 and XT [B][N][C] bf16
__global__ __launch_bounds__(256)
void pack_x_kernel(const float* __restrict__ x,
                   unsigned short* __restrict__ Xbf,
                   unsigned short* __restrict__ XT)
{
    __shared__ float tile[32][33];
    const int tx = threadIdx.x, ty = threadIdx.y;
    const int n0 = blockIdx.x * 32, c0 = blockIdx.y * 32, b = blockIdx.z;
    const size_t base = (size_t)b * CH * NSP;
#pragma unroll
    for (int i = ty; i < 32; i += 8) {
        float v = x[base + (size_t)(c0 + i) * NSP + n0 + tx];
        tile[i][tx] = v;
        Xbf[base + (size_t)(c0 + i) * NSP + n0 + tx] = f2bf(v);
    }
    __syncthreads();
    const size_t tbase = (size_t)b * NSP * CH;
#pragma unroll
    for (int i = ty; i < 32; i += 8)
        XT[tbase + (size_t)(n0 + i) * CH + c0 + tx] = f2bf(tile[tx][i]);
}

__global__ __launch_bounds__(256)
void cast_bf16_kernel(const float* __restrict__ src,
                      unsigned short* __restrict__ dst, int n)
{
    int i = blockIdx.x * 256 + threadIdx.x;
    if (i < n) dst[i] = f2bf(src[i]);
}

// in-place row softmax on bf16 scores, rows of length NSP=1024
__global__ __launch_bounds__(256)
void softmax_kernel(unsigned short* __restrict__ S)
{
    const int row = blockIdx.x;
    unsigned short* p = S + (size_t)row * NSP;
    const int t = threadIdx.x;

    ushort4 u = ((const ushort4*)p)[t];
    float v0 = bf2f(u.x), v1 = bf2f(u.y), v2 = bf2f(u.z), v3 = bf2f(u.w);

    float m = fmaxf(fmaxf(v0, v1), fmaxf(v2, v3));
#pragma unroll
    for (int off = 32; off > 0; off >>= 1) m = fmaxf(m, __shfl_xor(m, off));
    __shared__ float redmax[4], redsum[4];
    const int wid = t >> 6;
    if ((t & 63) == 0) redmax[wid] = m;
    __syncthreads();
    m = fmaxf(fmaxf(redmax[0], redmax[1]), fmaxf(redmax[2], redmax[3]));

    v0 = __expf(v0 - m); v1 = __expf(v1 - m);
    v2 = __expf(v2 - m); v3 = __expf(v3 - m);
    float s = v0 + v1 + v2 + v3;
#pragma unroll
    for (int off = 32; off > 0; off >>= 1) s += __shfl_xor(s, off);
    if ((t & 63) == 0) redsum[wid] = s;
    __syncthreads();
    s = redsum[0] + redsum[1] + redsum[2] + redsum[3];

    const float inv = 1.0f / s;
    ushort4 o;
    o.x = f2bf(v0 * inv); o.y = f2bf(v1 * inv);
    o.z = f2bf(v2 * inv); o.w = f2bf(v3 * inv);
    ((ushort4*)p)[t] = o;
}

extern "C" void kernel_launch(void* const* d_in, const int* in_sizes, int n_in,
                              void* d_out, int out_size, void* d_ws, size_t ws_size,
                              hipStream_t stream)
{
    const float* x  = (const float*)d_in[0];
    const float* w1 = (const float*)d_in[1];
    const float* b1 = (const float*)d_in[2];
    const float* w2 = (const float*)d_in[3];
    const float* b2 = (const float*)d_in[4];
    float* out = (float*)d_out;

    char* ws = (char*)d_ws;
    unsigned short* Xbf = (unsigned short*)ws; ws += (size_t)BATCH * CH * NSP * 2;   // 16 MB
    unsigned short* XT  = (unsigned short*)ws; ws += (size_t)BATCH * NSP * CH * 2;   // 16 MB
    unsigned short* W1b = (unsigned short*)ws; ws += (size_t)HIDD * CH * 2;          //  2 MB
    unsigned short* W2b = (unsigned short*)ws; ws += (size_t)CH * HIDD * 2;          //  2 MB
    unsigned short* P   = (unsigned short*)ws; ws += (size_t)BATCH * NSP * NSP * 2;  // 32 MB
    unsigned short* O   = (unsigned short*)ws; ws += (size_t)BATCH * NSP * CH * 2;   // 16 MB
    unsigned short* Hb  = (unsigned short*)ws; ws += (size_t)BATCH * NSP * HIDD * 2; // 64 MB

    const dim3 blk(256);

    // pack inputs to bf16 (X and X^T), weights to bf16
    pack_x_kernel<<<dim3(NSP / 32, CH / 32, BATCH), dim3(32, 8), 0, stream>>>(x, Xbf, XT);
    cast_bf16_kernel<<<dim3((HIDD * CH) / 256), blk, 0, stream>>>(w1, W1b, HIDD * CH);
    cast_bf16_kernel<<<dim3((CH * HIDD) / 256), blk, 0, stream>>>(w2, W2b, CH * HIDD);

    // S = scale * XT * XT^T   (per batch)  -> bf16 scores in P
    gemm_bt<0, 0><<<dim3(1024), blk, 0, stream>>>(
        XT, XT, P, NSP, CH,
        (long)NSP * CH, (long)NSP * CH, (long)NSP * NSP, nullptr,
        0.04419417382415922f, nullptr);

    // row softmax in place
    softmax_kernel<<<dim3(BATCH * NSP), blk, 0, stream>>>(P);

    // O = P * X^T  (B^T operand = Xbf [C][N])
    gemm_bt<1, 1><<<dim3(512), blk, 0, stream>>>(
        P, Xbf, O, CH, NSP,
        (long)NSP * NSP, (long)CH * NSP, (long)NSP * CH, nullptr, 1.f, nullptr);

    // H = relu(O * W1^T + b1)   (batches flattened into M)
    gemm_bt<2, 2><<<dim3(2048), blk, 0, stream>>>(
        O, W1b, Hb, HIDD, CH, 0, 0, 0, b1, 1.f, nullptr);

    // out = (W2 * H^T)[c][b*n] + b2[c] + x   — transposed epilogue
    gemm_bt<4, 3><<<dim3(512), blk, 0, stream>>>(
        W2b, Hb, out, BATCH * NSP, HIDD, 0, 0, 0, b2, 1.f, x);
}

// Round 8
// 276.639 us; speedup vs baseline: 1.3038x; 1.0070x over previous
//
#include <hip/hip_runtime.h>

#define BATCH 16
#define CH    512
#define NSP   1024
#define HIDD  2048

typedef __bf16 bf16x8 __attribute__((ext_vector_type(8)));
typedef float floatx4 __attribute__((ext_vector_type(4)));

__device__ __forceinline__ float bf2f(unsigned short u) {
    union { unsigned int i; float f; } v; v.i = ((unsigned int)u) << 16; return v.f;
}
__device__ __forceinline__ unsigned short f2bf(float f) {
    union { float f; unsigned int i; } v; v.f = f;
    unsigned int i = v.i;
    return (unsigned short)((i + 0x7FFFu + ((i >> 16) & 1u)) >> 16);
}

// async global->LDS, 16B per lane; LDS dst is wave-uniform base + lane*16
__device__ __forceinline__ void gload16(const void* g, void* l) {
    __builtin_amdgcn_global_load_lds(
        (__attribute__((address_space(1))) unsigned int*)(g),
        (__attribute__((address_space(3))) unsigned int*)(l),
        16, 0, 0);
}
#define MEMFENCE asm volatile("" ::: "memory")

// ---------------------------------------------------------------------------
// C = A (MxK, rm) * B^T (Bm NxK rm). 128x128 tile, BK=32, 4 waves,
// 4x4 mfma 16x16x32 per wave. XOR bank swizzle -> 0 conflicts (r2-verified).
//
// K-loop (r7-verified): DEPTH+1 LDS buffers, distance-DEPTH prefetch,
// 4 gload16 per wave per iter. Loop barrier is raw
//   s_waitcnt vmcnt(4*(DEPTH-1)); s_barrier
// -- waits only this wave's tile-'it' staging; newer prefetches stay in
// flight across the barrier (r7: 17->23% MfmaUtil, -25% dur vs vmcnt(0)).
//
// MAP: 0 scores: XCD owns 2 batches; 1 PV: XCD owns 2 batches;
//      3 out: XCD owns 16 n-tiles x 4 m (m fastest);
//      5 FFN1: XCD owns 16 m-tiles, sub-grouped 4 m x 16 n sweep
//              (512KB O-group + 2MB W1 = 2.5MB < 4MB L2; r4's full-stripe
//               4MB version thrashed).
// EPI: 0 scale->bf16 ; 1 plain->bf16 ; 2 +bias,relu->bf16 ;
//      4 transposed fp32: C[i][j] -> out[(j>>10)*CH*NSP + i*NSP + (j&1023)]
//         + bias[i] + resid[same]
// ---------------------------------------------------------------------------
template<int EPI, int MAP, int DEPTH>
__global__ __launch_bounds__(256, (DEPTH == 2) ? 3 : 2)
void gemm_bt(const unsigned short* __restrict__ A,
             const unsigned short* __restrict__ Bm,
             void* __restrict__ Cout,
             int Nn, int K,
             long sAb, long sBb, long sCb,
             const float* __restrict__ bias, float scale,
             const float* __restrict__ resid)
{
    constexpr int NBUF = DEPTH + 1;
    __shared__ unsigned short sA[NBUF][128 * 32];   // NBUF x 8 KB
    __shared__ unsigned short sB[NBUF][128 * 32];

    const int tid  = threadIdx.x;
    const int lane = tid & 63;
    const int w    = tid >> 6;        // wave 0..3
    const int quad = lane >> 4;
    const int l15  = lane & 15;
    const int mw   = (w >> 1) * 64;
    const int nw   = (w & 1) * 64;

    const int F = blockIdx.x;
    int m0, n0, b;
    if constexpr (MAP == 0) {        // 1024 blocks: 2 batches/XCD, 8x8 tiles
        const int xcd = F & 7, s = F >> 3;
        b = xcd + ((s >> 6) << 3);
        const int j = s & 63; m0 = (j >> 3) << 7; n0 = (j & 7) << 7;
    } else if constexpr (MAP == 1) { // 512 blocks: 2 batches/XCD, 8x4 tiles
        const int xcd = F & 7, s = F >> 3;
        b = xcd + ((s >> 5) << 3);
        const int j = s & 31; m0 = (j >> 2) << 7; n0 = (j & 3) << 7;
    } else if constexpr (MAP == 3) { // 512 blocks: 16 n-tiles/XCD x 4 m
        const int xcd = F & 7, s = F >> 3;
        b = 0; m0 = (s & 3) << 7; n0 = ((xcd << 4) + (s >> 2)) << 7;
    } else {                         // MAP 5: 2048 blocks, FFN1 sub-grouped
        const int xcd = F & 7, s = F >> 3;          // s in [0,256)
        const int g  = s >> 6;                      // m-group of 4 tiles
        const int nn = (s >> 2) & 15;               // n-tile (swept)
        const int mi = s & 3;                       // m within group (fastest)
        b = 0;
        m0 = ((xcd << 4) + (g << 2) + mi) << 7;
        n0 = nn << 7;
    }

    A  += (size_t)b * sAb;
    Bm += (size_t)b * sBb;

    // staging: wave w covers tile rows [w*32, w*32+32); each gload16 fills
    // 16 rows (lane>>2 = row, lane&3 = LDS granule slot). Granule swizzle:
    // LDS(row,s) = global(row, s^((row>>1)&3)).
    const int srow = lane >> 2;                       // 0..15
    const int sg   = (lane & 3) ^ ((lane >> 3) & 3);  // swizzled global granule
    const unsigned short* pA = A  + (size_t)(m0 + w * 32 + srow) * K + sg * 8;
    const unsigned short* pB = Bm + (size_t)(n0 + w * 32 + srow) * K + sg * 8;
    const size_t rowskip16 = (size_t)16 * K;
    const int woff = w * 1024;
    const int rslot = ((l15 >> 1) & 3);

    floatx4 acc[4][4];
#pragma unroll
    for (int i = 0; i < 4; i++)
#pragma unroll
        for (int j = 0; j < 4; j++) acc[i][j] = (floatx4){0.f, 0.f, 0.f, 0.f};

    const int nIter = K >> 5;
    const int kLast = K - 32;

    // prologue: stage tiles 0..DEPTH-1 into buffers 0..DEPTH-1
#pragma unroll
    for (int d = 0; d < DEPTH; ++d) {
        unsigned short* dA = &sA[d][0] + woff;
        unsigned short* dB = &sB[d][0] + woff;
        gload16(pA + d * 32,             dA);
        gload16(pA + d * 32 + rowskip16, dA + 512);
        gload16(pB + d * 32,             dB);
        gload16(pB + d * 32 + rowskip16, dB + 512);
        MEMFENCE;
    }

    int bcur = 0, bpf = DEPTH;  // buffer of tile 'it' / buffer for tile it+DEPTH
    for (int it = 0; it < nIter; ++it) {
        // tile 'it' staging retired; newer prefetches stay in flight
        if constexpr (DEPTH == 2)
            asm volatile("s_waitcnt vmcnt(4)\n\ts_barrier" ::: "memory");
        else
            asm volatile("s_waitcnt vmcnt(8)\n\ts_barrier" ::: "memory");

        // prefetch tile it+DEPTH into buf bpf (clamped dummy at tail)
        const int kpf = (it + DEPTH) * 32 <= kLast ? (it + DEPTH) * 32 : kLast;
        unsigned short* dA = &sA[0][0] + bpf * 4096 + woff;
        unsigned short* dB = &sB[0][0] + bpf * 4096 + woff;
        gload16(pA + kpf,             dA);
        gload16(pA + kpf + rowskip16, dA + 512);
        gload16(pB + kpf,             dB);
        gload16(pB + kpf + rowskip16, dB + 512);
        MEMFENCE;

        const unsigned short* bufA = &sA[0][0] + bcur * 4096;
        const unsigned short* bufB = &sB[0][0] + bcur * 4096;
        bf16x8 af[4], bfr[4];
#pragma unroll
        for (int mi = 0; mi < 4; mi++)
            af[mi] = *(const bf16x8*)(bufA + (mw + mi * 16 + l15) * 32
                                      + (quad ^ rslot) * 8);
#pragma unroll
        for (int ni = 0; ni < 4; ni++)
            bfr[ni] = *(const bf16x8*)(bufB + (nw + ni * 16 + l15) * 32
                                       + (quad ^ rslot) * 8);
#pragma unroll
        for (int mi = 0; mi < 4; mi++)
#pragma unroll
            for (int ni = 0; ni < 4; ni++)
                acc[mi][ni] = __builtin_amdgcn_mfma_f32_16x16x32_bf16(
                    af[mi], bfr[ni], acc[mi][ni], 0, 0, 0);

        bcur = bcur == NBUF - 1 ? 0 : bcur + 1;
        bpf  = bpf  == NBUF - 1 ? 0 : bpf  + 1;
    }
    // drain dummy prefetches before endpgm (LDS is reallocated to next block)
    asm volatile("s_waitcnt vmcnt(0)" ::: "memory");

    // epilogue: D row = quad*4 + reg, col = lane&15  (m89/m91-verified layout)
    if constexpr (EPI == 4) {
        float* Of = (float*)Cout;
#pragma unroll
        for (int ni = 0; ni < 4; ni++) {
            const int j  = n0 + nw + ni * 16 + l15;
            const int bb = j >> 10, ns = j & 1023;
            const size_t cbase = (size_t)bb * CH * NSP + ns;
#pragma unroll
            for (int mi = 0; mi < 4; mi++) {
                const int ibase = m0 + mw + mi * 16 + quad * 4;
#pragma unroll
                for (int r = 0; r < 4; r++) {
                    const int c = ibase + r;
                    const size_t a = cbase + (size_t)c * NSP;
                    Of[a] = acc[mi][ni][r] + bias[c] + resid[a];
                }
            }
        }
    } else {
        unsigned short* Cb = (unsigned short*)Cout + (size_t)b * sCb;
#pragma unroll
        for (int ni = 0; ni < 4; ni++) {
            const int n = n0 + nw + ni * 16 + l15;
            float bv = 0.f;
            if constexpr (EPI == 2) bv = bias[n];
#pragma unroll
            for (int mi = 0; mi < 4; mi++) {
                const int mbase = m0 + mw + mi * 16 + quad * 4;
#pragma unroll
                for (int r = 0; r < 4; r++) {
                    float v = acc[mi][ni][r];
                    if constexpr (EPI == 0) v *= scale;
                    if constexpr (EPI == 2) v = fmaxf(v + bv, 0.f);
                    Cb[(size_t)(mbase + r) * Nn + n] = f2bf(v);
                }
            }
        }
    }
}

// x [B][C][N] fp32 -> Xbf [B][C][N] bf16 and XT [B][N][C] bf16
__global__ __launch_bounds__(256)
void pack_x_kernel(const float* __restrict__ x,
                   unsigned short* __restrict__ Xbf,
                   unsigned short* __restrict__ XT)
{
    __shared__ float tile[32][33];
    const int tx = threadIdx.x, ty = threadIdx.y;
    const int n0 = blockIdx.x * 32, c0 = blockIdx.y * 32, b = blockIdx.z;
    const size_t base = (size_t)b * CH * NSP;
#pragma unroll
    for (int i = ty; i < 32; i += 8) {
        float v = x[base + (size_t)(c0 + i) * NSP + n0 + tx];
        tile[i][tx] = v;
        Xbf[base + (size_t)(c0 + i) * NSP + n0 + tx] = f2bf(v);
    }
    __syncthreads();
    const size_t tbase = (size_t)b * NSP * CH;
#pragma unroll
    for (int i = ty; i < 32; i += 8)
        XT[tbase + (size_t)(n0 + i) * CH + c0 + tx] = f2bf(tile[tx][i]);
}

__global__ __launch_bounds__(256)
void cast_bf16_kernel(const float* __restrict__ src,
                      unsigned short* __restrict__ dst, int n)
{
    int i = blockIdx.x * 256 + threadIdx.x;
    if (i < n) dst[i] = f2bf(src[i]);
}

// in-place row softmax on bf16 scores, rows of length NSP=1024
__global__ __launch_bounds__(256)
void softmax_kernel(unsigned short* __restrict__ S)
{
    const int row = blockIdx.x;
    unsigned short* p = S + (size_t)row * NSP;
    const int t = threadIdx.x;

    ushort4 u = ((const ushort4*)p)[t];
    float v0 = bf2f(u.x), v1 = bf2f(u.y), v2 = bf2f(u.z), v3 = bf2f(u.w);

    float m = fmaxf(fmaxf(v0, v1), fmaxf(v2, v3));
#pragma unroll
    for (int off = 32; off > 0; off >>= 1) m = fmaxf(m, __shfl_xor(m, off));
    __shared__ float redmax[4], redsum[4];
    const int wid = t >> 6;
    if ((t & 63) == 0) redmax[wid] = m;
    __syncthreads();
    m = fmaxf(fmaxf(redmax[0], redmax[1]), fmaxf(redmax[2], redmax[3]));

    v0 = __expf(v0 - m); v1 = __expf(v1 - m);
    v2 = __expf(v2 - m); v3 = __expf(v3 - m);
    float s = v0 + v1 + v2 + v3;
#pragma unroll
    for (int off = 32; off > 0; off >>= 1) s += __shfl_xor(s, off);
    if ((t & 63) == 0) redsum[wid] = s;
    __syncthreads();
    s = redsum[0] + redsum[1] + redsum[2] + redsum[3];

    const float inv = 1.0f / s;
    ushort4 o;
    o.x = f2bf(v0 * inv); o.y = f2bf(v1 * inv);
    o.z = f2bf(v2 * inv); o.w = f2bf(v3 * inv);
    ((ushort4*)p)[t] = o;
}

extern "C" void kernel_launch(void* const* d_in, const int* in_sizes, int n_in,
                              void* d_out, int out_size, void* d_ws, size_t ws_size,
                              hipStream_t stream)
{
    const float* x  = (const float*)d_in[0];
    const float* w1 = (const float*)d_in[1];
    const float* b1 = (const float*)d_in[2];
    const float* w2 = (const float*)d_in[3];
    const float* b2 = (const float*)d_in[4];
    float* out = (float*)d_out;

    char* ws = (char*)d_ws;
    unsigned short* Xbf = (unsigned short*)ws; ws += (size_t)BATCH * CH * NSP * 2;   // 16 MB
    unsigned short* XT  = (unsigned short*)ws; ws += (size_t)BATCH * NSP * CH * 2;   // 16 MB
    unsigned short* W1b = (unsigned short*)ws; ws += (size_t)HIDD * CH * 2;          //  2 MB
    unsigned short* W2b = (unsigned short*)ws; ws += (size_t)CH * HIDD * 2;          //  2 MB
    unsigned short* P   = (unsigned short*)ws; ws += (size_t)BATCH * NSP * NSP * 2;  // 32 MB
    unsigned short* O   = (unsigned short*)ws; ws += (size_t)BATCH * NSP * CH * 2;   // 16 MB
    unsigned short* Hb  = (unsigned short*)ws; ws += (size_t)BATCH * NSP * HIDD * 2; // 64 MB

    const dim3 blk(256);

    // pack inputs to bf16 (X and X^T), weights to bf16
    pack_x_kernel<<<dim3(NSP / 32, CH / 32, BATCH), dim3(32, 8), 0, stream>>>(x, Xbf, XT);
    cast_bf16_kernel<<<dim3((HIDD * CH) / 256), blk, 0, stream>>>(w1, W1b, HIDD * CH);
    cast_bf16_kernel<<<dim3((CH * HIDD) / 256), blk, 0, stream>>>(w2, W2b, CH * HIDD);

    // S = scale * XT * XT^T   (per batch)  -> bf16 scores in P
    gemm_bt<0, 0, 2><<<dim3(1024), blk, 0, stream>>>(
        XT, XT, P, NSP, CH,
        (long)NSP * CH, (long)NSP * CH, (long)NSP * NSP, nullptr,
        0.04419417382415922f, nullptr);

    // row softmax in place
    softmax_kernel<<<dim3(BATCH * NSP), blk, 0, stream>>>(P);

    // O = P * X^T  (B^T operand = Xbf [C][N])
    gemm_bt<1, 1, 2><<<dim3(512), blk, 0, stream>>>(
        P, Xbf, O, CH, NSP,
        (long)NSP * NSP, (long)CH * NSP, (long)NSP * CH, nullptr, 1.f, nullptr);

    // H = relu(O * W1^T + b1)  — sub-grouped XCD map (L2-resident O+W1)
    gemm_bt<2, 5, 2><<<dim3(2048), blk, 0, stream>>>(
        O, W1b, Hb, HIDD, CH, 0, 0, 0, b1, 1.f, nullptr);

    // out = (W2 * H^T)[c][b*n] + b2[c] + x  — transposed epilogue, depth-3
    gemm_bt<4, 3, 3><<<dim3(512), blk, 0, stream>>>(
        W2b, Hb, out, BATCH * NSP, HIDD, 0, 0, 0, b2, 1.f, x);
}